// Round 5
// baseline (1230.274 us; speedup 1.0000x reference)
//
#include <hip/hip_runtime.h>

#define NEDGE 800000
#define NNODE 50000
// dims: IN=16, HID=64, OUT=2

// ---------------------------------------------------------------------------
// wt = W_top - W_bot for both layers' first linear.
// w1a: [32,64] rows 0..15 = xi, 16..31 = (xj-xi).  w2a: [128,64] similarly.
// ---------------------------------------------------------------------------
__global__ void prep_weights(const float* __restrict__ w1a,
                             const float* __restrict__ w2a,
                             float* __restrict__ wt1,
                             float* __restrict__ wt2) {
    int i = blockIdx.x * blockDim.x + threadIdx.x;
    if (i < 16 * 64) wt1[i] = w1a[i] - w1a[16 * 64 + i];
    if (i < 64 * 64) wt2[i] = w2a[i] - w2a[64 * 64 + i];
}

// ---------------------------------------------------------------------------
// CSR build step 1: histogram of dst
// ---------------------------------------------------------------------------
__global__ __launch_bounds__(256) void edge_hist(const int* __restrict__ ei,
                                                 int* __restrict__ hist) {
    int e = blockIdx.x * blockDim.x + threadIdx.x;
    if (e >= NEDGE) return;
    atomicAdd(hist + ei[NEDGE + e], 1);
}

// ---------------------------------------------------------------------------
// CSR build step 2: exclusive scan of hist -> row_ptr (+cursor copy).
// Single block of 1024 threads; each thread owns 49 nodes serially,
// Hillis-Steele inclusive scan of the 1024 partial sums in LDS.
// ---------------------------------------------------------------------------
__global__ __launch_bounds__(1024) void scan_hist(const int* __restrict__ hist,
                                                  int* __restrict__ row_ptr,
                                                  int* __restrict__ cursor) {
    __shared__ int sh[1024];
    int t = threadIdx.x;
    const int C = (NNODE + 1023) / 1024;  // 49
    int base = t * C;
    int local = 0;
    for (int i = 0; i < C; ++i) {
        int n = base + i;
        if (n < NNODE) local += hist[n];
    }
    sh[t] = local;
    __syncthreads();
    for (int off = 1; off < 1024; off <<= 1) {
        int v = (t >= off) ? sh[t - off] : 0;
        __syncthreads();
        sh[t] += v;
        __syncthreads();
    }
    int run = sh[t] - local;  // exclusive offset for this thread's chunk
    for (int i = 0; i < C; ++i) {
        int n = base + i;
        if (n < NNODE) {
            row_ptr[n] = run;
            cursor[n] = run;
            run += hist[n];
        }
    }
    if (t == 1023) row_ptr[NNODE] = sh[1023];  // == NEDGE
}

// ---------------------------------------------------------------------------
// CSR build step 3: fill column (src) list
// ---------------------------------------------------------------------------
__global__ __launch_bounds__(256) void edge_fill(const int* __restrict__ ei,
                                                 int* __restrict__ cursor,
                                                 int* __restrict__ col_src) {
    int e = blockIdx.x * blockDim.x + threadIdx.x;
    if (e >= NEDGE) return;
    int s = ei[e];
    int d = ei[NEDGE + e];
    int slot = atomicAdd(cursor + d, 1);
    col_src[slot] = s;
}

// ---------------------------------------------------------------------------
// Layer-1 per-node precompute: pA[n] = x[n]@wt1 + b1a,  pB[n] = x[n]@wb1
// ---------------------------------------------------------------------------
__global__ __launch_bounds__(256) void node_pre1(
    const float* __restrict__ x, const float* __restrict__ wt1,
    const float* __restrict__ wb1, const float* __restrict__ b1a,
    float* __restrict__ pA, float* __restrict__ pB) {
    int n = blockIdx.x * blockDim.x + threadIdx.x;
    if (n >= NNODE) return;
    float xr[16];
    const float4* x4 = (const float4*)(x + n * 16);
#pragma unroll
    for (int q = 0; q < 4; ++q) {
        float4 v = x4[q];
        xr[q * 4 + 0] = v.x; xr[q * 4 + 1] = v.y;
        xr[q * 4 + 2] = v.z; xr[q * 4 + 3] = v.w;
    }
    float o[64];
#pragma unroll
    for (int j = 0; j < 64; ++j) o[j] = b1a[j];
#pragma unroll
    for (int k = 0; k < 16; ++k)
#pragma unroll
        for (int j = 0; j < 64; ++j) o[j] = fmaf(xr[k], wt1[k * 64 + j], o[j]);
    float4* oA = (float4*)(pA + n * 64);
#pragma unroll
    for (int q = 0; q < 16; ++q)
        oA[q] = make_float4(o[q * 4], o[q * 4 + 1], o[q * 4 + 2], o[q * 4 + 3]);

#pragma unroll
    for (int j = 0; j < 64; ++j) o[j] = 0.0f;
#pragma unroll
    for (int k = 0; k < 16; ++k)
#pragma unroll
        for (int j = 0; j < 64; ++j) o[j] = fmaf(xr[k], wb1[k * 64 + j], o[j]);
    float4* oB = (float4*)(pB + n * 64);
#pragma unroll
    for (int q = 0; q < 16; ++q)
        oB[q] = make_float4(o[q * 4], o[q * 4 + 1], o[q * 4 + 2], o[q * 4 + 3]);
}

// ---------------------------------------------------------------------------
// Strategy A (layer 1): atomic edge scatter, 16 lanes per edge.
//   acc[dst] += relu(pA[dst] + pB[src]);  cnt[dst] += 1
// ---------------------------------------------------------------------------
__global__ __launch_bounds__(256) void edge_scatter(
    const float* __restrict__ pA, const float* __restrict__ pB,
    const int* __restrict__ ei, float* __restrict__ acc,
    float* __restrict__ cnt, int doCount) {
    int t = blockIdx.x * blockDim.x + threadIdx.x;
    if (t >= NEDGE * 16) return;
    int e = t >> 4;
    int c = t & 15;
    int s = ei[e];
    int d = ei[NEDGE + e];
    float4 av = *(const float4*)(pA + (size_t)d * 64 + c * 4);
    float4 bv = *(const float4*)(pB + (size_t)s * 64 + c * 4);
    float* ap = acc + (size_t)d * 64 + c * 4;
    unsafeAtomicAdd(ap + 0, fmaxf(av.x + bv.x, 0.0f));
    unsafeAtomicAdd(ap + 1, fmaxf(av.y + bv.y, 0.0f));
    unsafeAtomicAdd(ap + 2, fmaxf(av.z + bv.z, 0.0f));
    unsafeAtomicAdd(ap + 3, fmaxf(av.w + bv.w, 0.0f));
    if (doCount && c == 0) unsafeAtomicAdd(cnt + d, 1.0f);
}

// ---------------------------------------------------------------------------
// Strategy B (layer 2): CSR aggregation, 16 lanes per node, zero f32 atomics.
//   acc[n] = sum_e relu(pA[n] + pB[col_src[e]]);  cnt[n] = deg(n)
// ---------------------------------------------------------------------------
__global__ __launch_bounds__(256) void csr_aggregate(
    const float* __restrict__ pA, const float* __restrict__ pB,
    const int* __restrict__ row_ptr, const int* __restrict__ col_src,
    float* __restrict__ acc, float* __restrict__ cnt) {
    int t = blockIdx.x * blockDim.x + threadIdx.x;
    int n = t >> 4;
    int c = t & 15;
    if (n >= NNODE) return;
    int beg = row_ptr[n];
    int end = row_ptr[n + 1];
    float4 av = *(const float4*)(pA + (size_t)n * 64 + c * 4);
    float sx = 0.0f, sy = 0.0f, sz = 0.0f, sw = 0.0f;
    for (int e = beg; e < end; ++e) {
        int s = col_src[e];
        float4 bv = *(const float4*)(pB + (size_t)s * 64 + c * 4);
        sx += fmaxf(av.x + bv.x, 0.0f);
        sy += fmaxf(av.y + bv.y, 0.0f);
        sz += fmaxf(av.z + bv.z, 0.0f);
        sw += fmaxf(av.w + bv.w, 0.0f);
    }
    *(float4*)(acc + (size_t)n * 64 + c * 4) = make_float4(sx, sy, sz, sw);
    if (c == 0) cnt[n] = (float)(end - beg);
}

// ---------------------------------------------------------------------------
// node_mid: h1 = relu( (acc/cnt)@w1b + b1b )  (0 if cnt==0),
// then layer-2 precompute: pA = h1@wt2 + b2a, pB = h1@wb2
// ---------------------------------------------------------------------------
__global__ __launch_bounds__(256) void node_mid(
    const float* __restrict__ acc, const float* __restrict__ cnt,
    const float* __restrict__ w1b, const float* __restrict__ b1b,
    const float* __restrict__ wt2, const float* __restrict__ wb2,
    const float* __restrict__ b2a,
    float* __restrict__ pA, float* __restrict__ pB) {
    int n = blockIdx.x * blockDim.x + threadIdx.x;
    if (n >= NNODE) return;
    float h1[64];
    float c = cnt[n];
    if (c > 0.0f) {
        float inv = 1.0f / c;
        float m[64];
        const float4* a4 = (const float4*)(acc + (size_t)n * 64);
#pragma unroll
        for (int q = 0; q < 16; ++q) {
            float4 v = a4[q];
            m[q * 4 + 0] = v.x * inv; m[q * 4 + 1] = v.y * inv;
            m[q * 4 + 2] = v.z * inv; m[q * 4 + 3] = v.w * inv;
        }
#pragma unroll
        for (int j = 0; j < 64; ++j) h1[j] = b1b[j];
#pragma unroll
        for (int k = 0; k < 64; ++k)
#pragma unroll
            for (int j = 0; j < 64; ++j)
                h1[j] = fmaf(m[k], w1b[k * 64 + j], h1[j]);
#pragma unroll
        for (int j = 0; j < 64; ++j) h1[j] = fmaxf(h1[j], 0.0f);
    } else {
#pragma unroll
        for (int j = 0; j < 64; ++j) h1[j] = 0.0f;
    }

    float o[64];
#pragma unroll
    for (int j = 0; j < 64; ++j) o[j] = b2a[j];
#pragma unroll
    for (int k = 0; k < 64; ++k)
#pragma unroll
        for (int j = 0; j < 64; ++j) o[j] = fmaf(h1[k], wt2[k * 64 + j], o[j]);
    float4* oA = (float4*)(pA + (size_t)n * 64);
#pragma unroll
    for (int q = 0; q < 16; ++q)
        oA[q] = make_float4(o[q * 4], o[q * 4 + 1], o[q * 4 + 2], o[q * 4 + 3]);

#pragma unroll
    for (int j = 0; j < 64; ++j) o[j] = 0.0f;
#pragma unroll
    for (int k = 0; k < 64; ++k)
#pragma unroll
        for (int j = 0; j < 64; ++j) o[j] = fmaf(h1[k], wb2[k * 64 + j], o[j]);
    float4* oB = (float4*)(pB + (size_t)n * 64);
#pragma unroll
    for (int q = 0; q < 16; ++q)
        oB[q] = make_float4(o[q * 4], o[q * 4 + 1], o[q * 4 + 2], o[q * 4 + 3]);
}

// ---------------------------------------------------------------------------
// node_final: h2 = relu( (acc/cnt)@w2b + b2b )  (0 if cnt==0);
// out = h2@wl + bl
// ---------------------------------------------------------------------------
__global__ __launch_bounds__(256) void node_final(
    const float* __restrict__ acc, const float* __restrict__ cnt,
    const float* __restrict__ w2b, const float* __restrict__ b2b,
    const float* __restrict__ wl, const float* __restrict__ bl,
    float* __restrict__ out) {
    int n = blockIdx.x * blockDim.x + threadIdx.x;
    if (n >= NNODE) return;
    float o0 = bl[0], o1 = bl[1];
    float c = cnt[n];
    if (c > 0.0f) {
        float inv = 1.0f / c;
        float m[64];
        const float4* a4 = (const float4*)(acc + (size_t)n * 64);
#pragma unroll
        for (int q = 0; q < 16; ++q) {
            float4 v = a4[q];
            m[q * 4 + 0] = v.x * inv; m[q * 4 + 1] = v.y * inv;
            m[q * 4 + 2] = v.z * inv; m[q * 4 + 3] = v.w * inv;
        }
        float h2[64];
#pragma unroll
        for (int j = 0; j < 64; ++j) h2[j] = b2b[j];
#pragma unroll
        for (int k = 0; k < 64; ++k)
#pragma unroll
            for (int j = 0; j < 64; ++j)
                h2[j] = fmaf(m[k], w2b[k * 64 + j], h2[j]);
#pragma unroll
        for (int k = 0; k < 64; ++k) {
            float hr = fmaxf(h2[k], 0.0f);
            o0 = fmaf(hr, wl[k * 2 + 0], o0);
            o1 = fmaf(hr, wl[k * 2 + 1], o1);
        }
    }
    // c==0: h2 = 0 -> out = bl (o0/o1 already bl)
    out[n * 2 + 0] = o0;
    out[n * 2 + 1] = o1;
}

// ---------------------------------------------------------------------------
extern "C" void kernel_launch(void* const* d_in, const int* in_sizes, int n_in,
                              void* d_out, int out_size, void* d_ws, size_t ws_size,
                              hipStream_t stream) {
    const float* x   = (const float*)d_in[0];
    const int*   ei  = (const int*)d_in[1];
    const float* w1a = (const float*)d_in[2];
    const float* b1a = (const float*)d_in[3];
    const float* w1b = (const float*)d_in[4];
    const float* b1b = (const float*)d_in[5];
    const float* w2a = (const float*)d_in[6];
    const float* b2a = (const float*)d_in[7];
    const float* w2b = (const float*)d_in[8];
    const float* b2b = (const float*)d_in[9];
    const float* wl  = (const float*)d_in[10];
    const float* bl  = (const float*)d_in[11];
    float* out = (float*)d_out;

    // workspace layout
    float* acc   = (float*)d_ws;            // NNODE*64
    float* cnt   = acc + NNODE * 64;        // NNODE
    float* pA    = cnt + NNODE;             // NNODE*64
    float* pB    = pA + NNODE * 64;         // NNODE*64
    float* wt1   = pB + NNODE * 64;         // 16*64
    float* wt2   = wt1 + 16 * 64;           // 64*64
    int* hist    = (int*)(wt2 + 64 * 64);   // NNODE
    int* row_ptr = hist + NNODE;            // NNODE+1
    int* cursor  = row_ptr + NNODE + 1;     // NNODE
    int* col_src = cursor + NNODE;          // NEDGE

    const float* wb1 = w1a + 16 * 64;
    const float* wb2 = w2a + 64 * 64;

    const int NBLK  = (NNODE + 255) / 256;
    const int EBLK  = (NEDGE + 255) / 256;
    const int E16   = (NEDGE * 16 + 255) / 256;
    const int N16   = (NNODE * 16 + 255) / 256;

    prep_weights<<<16, 256, 0, stream>>>(w1a, w2a, wt1, wt2);
    node_pre1<<<NBLK, 256, 0, stream>>>(x, wt1, wb1, b1a, pA, pB);

    // CSR build (used by layer 2)
    hipMemsetAsync(hist, 0, (size_t)NNODE * sizeof(int), stream);
    edge_hist<<<EBLK, 256, 0, stream>>>(ei, hist);
    scan_hist<<<1, 1024, 0, stream>>>(hist, row_ptr, cursor);
    edge_fill<<<EBLK, 256, 0, stream>>>(ei, cursor, col_src);

    // Layer 1: atomic scatter strategy
    hipMemsetAsync(acc, 0, (size_t)(NNODE * 64 + NNODE) * sizeof(float), stream);
    edge_scatter<<<E16, 256, 0, stream>>>(pA, pB, ei, acc, cnt, 1);

    node_mid<<<NBLK, 256, 0, stream>>>(acc, cnt, w1b, b1b, wt2, wb2, b2a, pA, pB);

    // Layer 2: CSR aggregation strategy (no memset needed — fully overwritten)
    csr_aggregate<<<N16, 256, 0, stream>>>(pA, pB, row_ptr, col_src, acc, cnt);

    node_final<<<NBLK, 256, 0, stream>>>(acc, cnt, w2b, b2b, wl, bl, out);
}

// Round 7
// 538.505 us; speedup vs baseline: 2.2846x; 2.2846x over previous
//
#include <hip/hip_runtime.h>

#define NEDGE 800000
#define NNODE 50000
// dims: IN=16, HID=64, OUT=2

// ---------------------------------------------------------------------------
// wt = W_top - W_bot for both layers' first linear.
// w1a: [32,64] rows 0..15 = xi, 16..31 = (xj-xi).  w2a: [128,64] similarly.
// ---------------------------------------------------------------------------
__global__ void prep_weights(const float* __restrict__ w1a,
                             const float* __restrict__ w2a,
                             float* __restrict__ wt1,
                             float* __restrict__ wt2) {
    int i = blockIdx.x * blockDim.x + threadIdx.x;
    if (i < 16 * 64) wt1[i] = w1a[i] - w1a[16 * 64 + i];
    if (i < 64 * 64) wt2[i] = w2a[i] - w2a[64 * 64 + i];
}

// ---------------------------------------------------------------------------
// CSR build step 1: histogram of dst
// ---------------------------------------------------------------------------
__global__ __launch_bounds__(256) void edge_hist(const int* __restrict__ ei,
                                                 int* __restrict__ hist) {
    int e = blockIdx.x * blockDim.x + threadIdx.x;
    if (e >= NEDGE) return;
    atomicAdd(hist + ei[NEDGE + e], 1);
}

// ---------------------------------------------------------------------------
// CSR build step 2: exclusive scan of hist -> row_ptr (+cursor copy).
// Single block of 1024 threads; each thread owns 49 nodes serially,
// Hillis-Steele inclusive scan of the 1024 partial sums in LDS.
// ---------------------------------------------------------------------------
__global__ __launch_bounds__(1024) void scan_hist(const int* __restrict__ hist,
                                                  int* __restrict__ row_ptr,
                                                  int* __restrict__ cursor) {
    __shared__ int sh[1024];
    int t = threadIdx.x;
    const int C = (NNODE + 1023) / 1024;  // 49
    int base = t * C;
    int local = 0;
    for (int i = 0; i < C; ++i) {
        int n = base + i;
        if (n < NNODE) local += hist[n];
    }
    sh[t] = local;
    __syncthreads();
    for (int off = 1; off < 1024; off <<= 1) {
        int v = (t >= off) ? sh[t - off] : 0;
        __syncthreads();
        sh[t] += v;
        __syncthreads();
    }
    int run = sh[t] - local;  // exclusive offset for this thread's chunk
    for (int i = 0; i < C; ++i) {
        int n = base + i;
        if (n < NNODE) {
            row_ptr[n] = run;
            cursor[n] = run;
            run += hist[n];
        }
    }
    if (t == 1023) row_ptr[NNODE] = sh[1023];  // == NEDGE
}

// ---------------------------------------------------------------------------
// CSR build step 3: fill column (src) list
// ---------------------------------------------------------------------------
__global__ __launch_bounds__(256) void edge_fill(const int* __restrict__ ei,
                                                 int* __restrict__ cursor,
                                                 int* __restrict__ col_src) {
    int e = blockIdx.x * blockDim.x + threadIdx.x;
    if (e >= NEDGE) return;
    int s = ei[e];
    int d = ei[NEDGE + e];
    int slot = atomicAdd(cursor + d, 1);
    col_src[slot] = s;
}

// ---------------------------------------------------------------------------
// Layer-1 per-node precompute: pA[n] = x[n]@wt1 + b1a,  pB[n] = x[n]@wb1
// ---------------------------------------------------------------------------
__global__ __launch_bounds__(256) void node_pre1(
    const float* __restrict__ x, const float* __restrict__ wt1,
    const float* __restrict__ wb1, const float* __restrict__ b1a,
    float* __restrict__ pA, float* __restrict__ pB) {
    int n = blockIdx.x * blockDim.x + threadIdx.x;
    if (n >= NNODE) return;
    float xr[16];
    const float4* x4 = (const float4*)(x + n * 16);
#pragma unroll
    for (int q = 0; q < 4; ++q) {
        float4 v = x4[q];
        xr[q * 4 + 0] = v.x; xr[q * 4 + 1] = v.y;
        xr[q * 4 + 2] = v.z; xr[q * 4 + 3] = v.w;
    }
    float o[64];
#pragma unroll
    for (int j = 0; j < 64; ++j) o[j] = b1a[j];
#pragma unroll
    for (int k = 0; k < 16; ++k)
#pragma unroll
        for (int j = 0; j < 64; ++j) o[j] = fmaf(xr[k], wt1[k * 64 + j], o[j]);
    float4* oA = (float4*)(pA + n * 64);
#pragma unroll
    for (int q = 0; q < 16; ++q)
        oA[q] = make_float4(o[q * 4], o[q * 4 + 1], o[q * 4 + 2], o[q * 4 + 3]);

#pragma unroll
    for (int j = 0; j < 64; ++j) o[j] = 0.0f;
#pragma unroll
    for (int k = 0; k < 16; ++k)
#pragma unroll
        for (int j = 0; j < 64; ++j) o[j] = fmaf(xr[k], wb1[k * 64 + j], o[j]);
    float4* oB = (float4*)(pB + n * 64);
#pragma unroll
    for (int q = 0; q < 16; ++q)
        oB[q] = make_float4(o[q * 4], o[q * 4 + 1], o[q * 4 + 2], o[q * 4 + 3]);
}

// ---------------------------------------------------------------------------
// CSR aggregation, 16 lanes per node, zero f32 atomics:
//   acc[n] = sum_e relu(pA[n] + pB[col_src[e]]);  cnt[n] = deg(n)
// ---------------------------------------------------------------------------
__global__ __launch_bounds__(256) void csr_aggregate(
    const float* __restrict__ pA, const float* __restrict__ pB,
    const int* __restrict__ row_ptr, const int* __restrict__ col_src,
    float* __restrict__ acc, float* __restrict__ cnt) {
    int t = blockIdx.x * blockDim.x + threadIdx.x;
    int n = t >> 4;
    int c = t & 15;
    if (n >= NNODE) return;
    int beg = row_ptr[n];
    int end = row_ptr[n + 1];
    float4 av = *(const float4*)(pA + (size_t)n * 64 + c * 4);
    float sx = 0.0f, sy = 0.0f, sz = 0.0f, sw = 0.0f;
    for (int e = beg; e < end; ++e) {
        int s = col_src[e];
        float4 bv = *(const float4*)(pB + (size_t)s * 64 + c * 4);
        sx += fmaxf(av.x + bv.x, 0.0f);
        sy += fmaxf(av.y + bv.y, 0.0f);
        sz += fmaxf(av.z + bv.z, 0.0f);
        sw += fmaxf(av.w + bv.w, 0.0f);
    }
    *(float4*)(acc + (size_t)n * 64 + c * 4) = make_float4(sx, sy, sz, sw);
    if (c == 0) cnt[n] = (float)(end - beg);
}

// ---------------------------------------------------------------------------
// node_mid: h1 = relu( (acc/cnt)@w1b + b1b )  (0 if cnt==0),
// then layer-2 precompute: pA = h1@wt2 + b2a, pB = h1@wb2
// ---------------------------------------------------------------------------
__global__ __launch_bounds__(256) void node_mid(
    const float* __restrict__ acc, const float* __restrict__ cnt,
    const float* __restrict__ w1b, const float* __restrict__ b1b,
    const float* __restrict__ wt2, const float* __restrict__ wb2,
    const float* __restrict__ b2a,
    float* __restrict__ pA, float* __restrict__ pB) {
    int n = blockIdx.x * blockDim.x + threadIdx.x;
    if (n >= NNODE) return;
    float h1[64];
    float c = cnt[n];
    if (c > 0.0f) {
        float inv = 1.0f / c;
        float m[64];
        const float4* a4 = (const float4*)(acc + (size_t)n * 64);
#pragma unroll
        for (int q = 0; q < 16; ++q) {
            float4 v = a4[q];
            m[q * 4 + 0] = v.x * inv; m[q * 4 + 1] = v.y * inv;
            m[q * 4 + 2] = v.z * inv; m[q * 4 + 3] = v.w * inv;
        }
#pragma unroll
        for (int j = 0; j < 64; ++j) h1[j] = b1b[j];
#pragma unroll
        for (int k = 0; k < 64; ++k)
#pragma unroll
            for (int j = 0; j < 64; ++j)
                h1[j] = fmaf(m[k], w1b[k * 64 + j], h1[j]);
#pragma unroll
        for (int j = 0; j < 64; ++j) h1[j] = fmaxf(h1[j], 0.0f);
    } else {
#pragma unroll
        for (int j = 0; j < 64; ++j) h1[j] = 0.0f;
    }

    float o[64];
#pragma unroll
    for (int j = 0; j < 64; ++j) o[j] = b2a[j];
#pragma unroll
    for (int k = 0; k < 64; ++k)
#pragma unroll
        for (int j = 0; j < 64; ++j) o[j] = fmaf(h1[k], wt2[k * 64 + j], o[j]);
    float4* oA = (float4*)(pA + (size_t)n * 64);
#pragma unroll
    for (int q = 0; q < 16; ++q)
        oA[q] = make_float4(o[q * 4], o[q * 4 + 1], o[q * 4 + 2], o[q * 4 + 3]);

#pragma unroll
    for (int j = 0; j < 64; ++j) o[j] = 0.0f;
#pragma unroll
    for (int k = 0; k < 64; ++k)
#pragma unroll
        for (int j = 0; j < 64; ++j) o[j] = fmaf(h1[k], wb2[k * 64 + j], o[j]);
    float4* oB = (float4*)(pB + (size_t)n * 64);
#pragma unroll
    for (int q = 0; q < 16; ++q)
        oB[q] = make_float4(o[q * 4], o[q * 4 + 1], o[q * 4 + 2], o[q * 4 + 3]);
}

// ---------------------------------------------------------------------------
// node_final: h2 = relu( (acc/cnt)@w2b + b2b )  (0 if cnt==0);
// out = h2@wl + bl
// ---------------------------------------------------------------------------
__global__ __launch_bounds__(256) void node_final(
    const float* __restrict__ acc, const float* __restrict__ cnt,
    const float* __restrict__ w2b, const float* __restrict__ b2b,
    const float* __restrict__ wl, const float* __restrict__ bl,
    float* __restrict__ out) {
    int n = blockIdx.x * blockDim.x + threadIdx.x;
    if (n >= NNODE) return;
    float o0 = bl[0], o1 = bl[1];
    float c = cnt[n];
    if (c > 0.0f) {
        float inv = 1.0f / c;
        float m[64];
        const float4* a4 = (const float4*)(acc + (size_t)n * 64);
#pragma unroll
        for (int q = 0; q < 16; ++q) {
            float4 v = a4[q];
            m[q * 4 + 0] = v.x * inv; m[q * 4 + 1] = v.y * inv;
            m[q * 4 + 2] = v.z * inv; m[q * 4 + 3] = v.w * inv;
        }
        float h2[64];
#pragma unroll
        for (int j = 0; j < 64; ++j) h2[j] = b2b[j];
#pragma unroll
        for (int k = 0; k < 64; ++k)
#pragma unroll
            for (int j = 0; j < 64; ++j)
                h2[j] = fmaf(m[k], w2b[k * 64 + j], h2[j]);
#pragma unroll
        for (int k = 0; k < 64; ++k) {
            float hr = fmaxf(h2[k], 0.0f);
            o0 = fmaf(hr, wl[k * 2 + 0], o0);
            o1 = fmaf(hr, wl[k * 2 + 1], o1);
        }
    }
    // c==0: h2 = 0 -> out = bl (o0/o1 already bl)
    out[n * 2 + 0] = o0;
    out[n * 2 + 1] = o1;
}

// ---------------------------------------------------------------------------
extern "C" void kernel_launch(void* const* d_in, const int* in_sizes, int n_in,
                              void* d_out, int out_size, void* d_ws, size_t ws_size,
                              hipStream_t stream) {
    const float* x   = (const float*)d_in[0];
    const int*   ei  = (const int*)d_in[1];
    const float* w1a = (const float*)d_in[2];
    const float* b1a = (const float*)d_in[3];
    const float* w1b = (const float*)d_in[4];
    const float* b1b = (const float*)d_in[5];
    const float* w2a = (const float*)d_in[6];
    const float* b2a = (const float*)d_in[7];
    const float* w2b = (const float*)d_in[8];
    const float* b2b = (const float*)d_in[9];
    const float* wl  = (const float*)d_in[10];
    const float* bl  = (const float*)d_in[11];
    float* out = (float*)d_out;

    // workspace layout
    float* acc   = (float*)d_ws;            // NNODE*64
    float* cnt   = acc + NNODE * 64;        // NNODE
    float* pA    = cnt + NNODE;             // NNODE*64
    float* pB    = pA + NNODE * 64;         // NNODE*64
    float* wt1   = pB + NNODE * 64;         // 16*64
    float* wt2   = wt1 + 16 * 64;           // 64*64
    int* hist    = (int*)(wt2 + 64 * 64);   // NNODE
    int* row_ptr = hist + NNODE;            // NNODE+1
    int* cursor  = row_ptr + NNODE + 1;     // NNODE
    int* col_src = cursor + NNODE;          // NEDGE

    const float* wb1 = w1a + 16 * 64;
    const float* wb2 = w2a + 64 * 64;

    const int NBLK = (NNODE + 255) / 256;
    const int EBLK = (NEDGE + 255) / 256;
    const int N16  = (NNODE * 16 + 255) / 256;

    // CSR build (shared by both layers)
    hipMemsetAsync(hist, 0, (size_t)NNODE * sizeof(int), stream);
    edge_hist<<<EBLK, 256, 0, stream>>>(ei, hist);
    scan_hist<<<1, 1024, 0, stream>>>(hist, row_ptr, cursor);
    edge_fill<<<EBLK, 256, 0, stream>>>(ei, cursor, col_src);

    prep_weights<<<16, 256, 0, stream>>>(w1a, w2a, wt1, wt2);
    node_pre1<<<NBLK, 256, 0, stream>>>(x, wt1, wb1, b1a, pA, pB);

    // Layer 1: CSR aggregation
    csr_aggregate<<<N16, 256, 0, stream>>>(pA, pB, row_ptr, col_src, acc, cnt);

    node_mid<<<NBLK, 256, 0, stream>>>(acc, cnt, w1b, b1b, wt2, wb2, b2a, pA, pB);

    // Layer 2: CSR aggregation
    csr_aggregate<<<N16, 256, 0, stream>>>(pA, pB, row_ptr, col_src, acc, cnt);

    node_final<<<NBLK, 256, 0, stream>>>(acc, cnt, w2b, b2b, wl, bl, out);
}

// Round 11
// 426.203 us; speedup vs baseline: 2.8866x; 1.2635x over previous
//
#include <hip/hip_runtime.h>

#define NEDGE 800000
#define NNODE 50000
#define NSBLK ((NNODE + 255) / 256)   // 196 scan blocks
// dims: IN=16, HID=64, OUT=2

// ---------------------------------------------------------------------------
// wt = W_top - W_bot for both layers' first linear.
// w1a: [32,64] rows 0..15 = xi, 16..31 = (xj-xi).  w2a: [128,64] similarly.
// ---------------------------------------------------------------------------
__global__ void prep_weights(const float* __restrict__ w1a,
                             const float* __restrict__ w2a,
                             float* __restrict__ wt1,
                             float* __restrict__ wt2) {
    int i = blockIdx.x * blockDim.x + threadIdx.x;
    if (i < 16 * 64) wt1[i] = w1a[i] - w1a[16 * 64 + i];
    if (i < 64 * 64) wt2[i] = w2a[i] - w2a[64 * 64 + i];
}

// ---------------------------------------------------------------------------
// CSR build step 1: histogram of dst
// ---------------------------------------------------------------------------
__global__ __launch_bounds__(256) void edge_hist(const int* __restrict__ ei,
                                                 int* __restrict__ hist) {
    int e = blockIdx.x * blockDim.x + threadIdx.x;
    if (e >= NEDGE) return;
    atomicAdd(hist + ei[NEDGE + e], 1);
}

// ---------------------------------------------------------------------------
// CSR build step 2: multi-block exclusive scan of hist -> row_ptr, cursor.
// Phase A: per-block tree-reduce -> blockSums[NSBLK]
// Phase B: single-block exclusive scan of blockSums -> blockOff
// Phase C: per-block exclusive scan + blockOff -> row_ptr/cursor (coalesced)
// ---------------------------------------------------------------------------
__global__ __launch_bounds__(256) void scan_phase_a(const int* __restrict__ hist,
                                                    int* __restrict__ blockSums) {
    __shared__ int sh[256];
    int t = threadIdx.x;
    int n = blockIdx.x * 256 + t;
    sh[t] = (n < NNODE) ? hist[n] : 0;
    __syncthreads();
#pragma unroll
    for (int off = 128; off > 0; off >>= 1) {
        if (t < off) sh[t] += sh[t + off];
        __syncthreads();
    }
    if (t == 0) blockSums[blockIdx.x] = sh[0];
}

__global__ __launch_bounds__(256) void scan_phase_b(const int* __restrict__ blockSums,
                                                    int* __restrict__ blockOff) {
    __shared__ int sh[256];
    int t = threadIdx.x;
    int v = (t < NSBLK) ? blockSums[t] : 0;
    sh[t] = v;
    __syncthreads();
#pragma unroll
    for (int off = 1; off < 256; off <<= 1) {
        int u = (t >= off) ? sh[t - off] : 0;
        __syncthreads();
        sh[t] += u;
        __syncthreads();
    }
    if (t < NSBLK) blockOff[t] = sh[t] - v;  // exclusive
}

__global__ __launch_bounds__(256) void scan_phase_c(const int* __restrict__ hist,
                                                    const int* __restrict__ blockOff,
                                                    int* __restrict__ row_ptr,
                                                    int* __restrict__ cursor) {
    __shared__ int sh[256];
    int t = threadIdx.x;
    int n = blockIdx.x * 256 + t;
    int v = (n < NNODE) ? hist[n] : 0;
    sh[t] = v;
    __syncthreads();
#pragma unroll
    for (int off = 1; off < 256; off <<= 1) {
        int u = (t >= off) ? sh[t - off] : 0;
        __syncthreads();
        sh[t] += u;
        __syncthreads();
    }
    int ex = blockOff[blockIdx.x] + sh[t] - v;  // exclusive prefix
    if (n < NNODE) {
        row_ptr[n] = ex;
        cursor[n] = ex;
    }
    if (blockIdx.x == 0 && t == 0) row_ptr[NNODE] = NEDGE;  // total is constant
}

// ---------------------------------------------------------------------------
// CSR build step 3: fill column (src) list
// ---------------------------------------------------------------------------
__global__ __launch_bounds__(256) void edge_fill(const int* __restrict__ ei,
                                                 int* __restrict__ cursor,
                                                 int* __restrict__ col_src) {
    int e = blockIdx.x * blockDim.x + threadIdx.x;
    if (e >= NEDGE) return;
    int s = ei[e];
    int d = ei[NEDGE + e];
    int slot = atomicAdd(cursor + d, 1);
    col_src[slot] = s;
}

// ---------------------------------------------------------------------------
// Layer-1 per-node precompute: pA[n] = x[n]@wt1 + b1a,  pB[n] = x[n]@wb1
// ---------------------------------------------------------------------------
__global__ __launch_bounds__(256) void node_pre1(
    const float* __restrict__ x, const float* __restrict__ wt1,
    const float* __restrict__ wb1, const float* __restrict__ b1a,
    float* __restrict__ pA, float* __restrict__ pB) {
    int n = blockIdx.x * blockDim.x + threadIdx.x;
    if (n >= NNODE) return;
    float xr[16];
    const float4* x4 = (const float4*)(x + n * 16);
#pragma unroll
    for (int q = 0; q < 4; ++q) {
        float4 v = x4[q];
        xr[q * 4 + 0] = v.x; xr[q * 4 + 1] = v.y;
        xr[q * 4 + 2] = v.z; xr[q * 4 + 3] = v.w;
    }
    float o[64];
#pragma unroll
    for (int j = 0; j < 64; ++j) o[j] = b1a[j];
#pragma unroll
    for (int k = 0; k < 16; ++k)
#pragma unroll
        for (int j = 0; j < 64; ++j) o[j] = fmaf(xr[k], wt1[k * 64 + j], o[j]);
    float4* oA = (float4*)(pA + n * 64);
#pragma unroll
    for (int q = 0; q < 16; ++q)
        oA[q] = make_float4(o[q * 4], o[q * 4 + 1], o[q * 4 + 2], o[q * 4 + 3]);

#pragma unroll
    for (int j = 0; j < 64; ++j) o[j] = 0.0f;
#pragma unroll
    for (int k = 0; k < 16; ++k)
#pragma unroll
        for (int j = 0; j < 64; ++j) o[j] = fmaf(xr[k], wb1[k * 64 + j], o[j]);
    float4* oB = (float4*)(pB + n * 64);
#pragma unroll
    for (int q = 0; q < 16; ++q)
        oB[q] = make_float4(o[q * 4], o[q * 4 + 1], o[q * 4 + 2], o[q * 4 + 3]);
}

// ---------------------------------------------------------------------------
// CSR aggregation, 16 lanes per node, zero f32 atomics:
//   acc[n] = sum_e relu(pA[n] + pB[col_src[e]]);  cnt[n] = deg(n)
// ---------------------------------------------------------------------------
__global__ __launch_bounds__(256) void csr_aggregate(
    const float* __restrict__ pA, const float* __restrict__ pB,
    const int* __restrict__ row_ptr, const int* __restrict__ col_src,
    float* __restrict__ acc, float* __restrict__ cnt) {
    int t = blockIdx.x * blockDim.x + threadIdx.x;
    int n = t >> 4;
    int c = t & 15;
    if (n >= NNODE) return;
    int beg = row_ptr[n];
    int end = row_ptr[n + 1];
    float4 av = *(const float4*)(pA + (size_t)n * 64 + c * 4);
    float sx = 0.0f, sy = 0.0f, sz = 0.0f, sw = 0.0f;
    for (int e = beg; e < end; ++e) {
        int s = col_src[e];
        float4 bv = *(const float4*)(pB + (size_t)s * 64 + c * 4);
        sx += fmaxf(av.x + bv.x, 0.0f);
        sy += fmaxf(av.y + bv.y, 0.0f);
        sz += fmaxf(av.z + bv.z, 0.0f);
        sw += fmaxf(av.w + bv.w, 0.0f);
    }
    *(float4*)(acc + (size_t)n * 64 + c * 4) = make_float4(sx, sy, sz, sw);
    if (c == 0) cnt[n] = (float)(end - beg);
}

// ---------------------------------------------------------------------------
// node_mid: h1 = relu( (acc/cnt)@w1b + b1b )  (0 if cnt==0),
// then layer-2 precompute: pA = h1@wt2 + b2a, pB = h1@wb2
// ---------------------------------------------------------------------------
__global__ __launch_bounds__(256) void node_mid(
    const float* __restrict__ acc, const float* __restrict__ cnt,
    const float* __restrict__ w1b, const float* __restrict__ b1b,
    const float* __restrict__ wt2, const float* __restrict__ wb2,
    const float* __restrict__ b2a,
    float* __restrict__ pA, float* __restrict__ pB) {
    int n = blockIdx.x * blockDim.x + threadIdx.x;
    if (n >= NNODE) return;
    float h1[64];
    float c = cnt[n];
    if (c > 0.0f) {
        float inv = 1.0f / c;
        float m[64];
        const float4* a4 = (const float4*)(acc + (size_t)n * 64);
#pragma unroll
        for (int q = 0; q < 16; ++q) {
            float4 v = a4[q];
            m[q * 4 + 0] = v.x * inv; m[q * 4 + 1] = v.y * inv;
            m[q * 4 + 2] = v.z * inv; m[q * 4 + 3] = v.w * inv;
        }
#pragma unroll
        for (int j = 0; j < 64; ++j) h1[j] = b1b[j];
#pragma unroll
        for (int k = 0; k < 64; ++k)
#pragma unroll
            for (int j = 0; j < 64; ++j)
                h1[j] = fmaf(m[k], w1b[k * 64 + j], h1[j]);
#pragma unroll
        for (int j = 0; j < 64; ++j) h1[j] = fmaxf(h1[j], 0.0f);
    } else {
#pragma unroll
        for (int j = 0; j < 64; ++j) h1[j] = 0.0f;
    }

    float o[64];
#pragma unroll
    for (int j = 0; j < 64; ++j) o[j] = b2a[j];
#pragma unroll
    for (int k = 0; k < 64; ++k)
#pragma unroll
        for (int j = 0; j < 64; ++j) o[j] = fmaf(h1[k], wt2[k * 64 + j], o[j]);
    float4* oA = (float4*)(pA + (size_t)n * 64);
#pragma unroll
    for (int q = 0; q < 16; ++q)
        oA[q] = make_float4(o[q * 4], o[q * 4 + 1], o[q * 4 + 2], o[q * 4 + 3]);

#pragma unroll
    for (int j = 0; j < 64; ++j) o[j] = 0.0f;
#pragma unroll
    for (int k = 0; k < 64; ++k)
#pragma unroll
        for (int j = 0; j < 64; ++j) o[j] = fmaf(h1[k], wb2[k * 64 + j], o[j]);
    float4* oB = (float4*)(pB + (size_t)n * 64);
#pragma unroll
    for (int q = 0; q < 16; ++q)
        oB[q] = make_float4(o[q * 4], o[q * 4 + 1], o[q * 4 + 2], o[q * 4 + 3]);
}

// ---------------------------------------------------------------------------
// node_final: h2 = relu( (acc/cnt)@w2b + b2b )  (0 if cnt==0);
// out = h2@wl + bl
// ---------------------------------------------------------------------------
__global__ __launch_bounds__(256) void node_final(
    const float* __restrict__ acc, const float* __restrict__ cnt,
    const float* __restrict__ w2b, const float* __restrict__ b2b,
    const float* __restrict__ wl, const float* __restrict__ bl,
    float* __restrict__ out) {
    int n = blockIdx.x * blockDim.x + threadIdx.x;
    if (n >= NNODE) return;
    float o0 = bl[0], o1 = bl[1];
    float c = cnt[n];
    if (c > 0.0f) {
        float inv = 1.0f / c;
        float m[64];
        const float4* a4 = (const float4*)(acc + (size_t)n * 64);
#pragma unroll
        for (int q = 0; q < 16; ++q) {
            float4 v = a4[q];
            m[q * 4 + 0] = v.x * inv; m[q * 4 + 1] = v.y * inv;
            m[q * 4 + 2] = v.z * inv; m[q * 4 + 3] = v.w * inv;
        }
        float h2[64];
#pragma unroll
        for (int j = 0; j < 64; ++j) h2[j] = b2b[j];
#pragma unroll
        for (int k = 0; k < 64; ++k)
#pragma unroll
            for (int j = 0; j < 64; ++j)
                h2[j] = fmaf(m[k], w2b[k * 64 + j], h2[j]);
#pragma unroll
        for (int k = 0; k < 64; ++k) {
            float hr = fmaxf(h2[k], 0.0f);
            o0 = fmaf(hr, wl[k * 2 + 0], o0);
            o1 = fmaf(hr, wl[k * 2 + 1], o1);
        }
    }
    // c==0: h2 = 0 -> out = bl (o0/o1 already bl)
    out[n * 2 + 0] = o0;
    out[n * 2 + 1] = o1;
}

// ---------------------------------------------------------------------------
extern "C" void kernel_launch(void* const* d_in, const int* in_sizes, int n_in,
                              void* d_out, int out_size, void* d_ws, size_t ws_size,
                              hipStream_t stream) {
    const float* x   = (const float*)d_in[0];
    const int*   ei  = (const int*)d_in[1];
    const float* w1a = (const float*)d_in[2];
    const float* b1a = (const float*)d_in[3];
    const float* w1b = (const float*)d_in[4];
    const float* b1b = (const float*)d_in[5];
    const float* w2a = (const float*)d_in[6];
    const float* b2a = (const float*)d_in[7];
    const float* w2b = (const float*)d_in[8];
    const float* b2b = (const float*)d_in[9];
    const float* wl  = (const float*)d_in[10];
    const float* bl  = (const float*)d_in[11];
    float* out = (float*)d_out;

    // workspace layout
    float* acc    = (float*)d_ws;            // NNODE*64
    float* cnt    = acc + NNODE * 64;        // NNODE
    float* pA     = cnt + NNODE;             // NNODE*64
    float* pB     = pA + NNODE * 64;         // NNODE*64
    float* wt1    = pB + NNODE * 64;         // 16*64
    float* wt2    = wt1 + 16 * 64;           // 64*64
    int* hist     = (int*)(wt2 + 64 * 64);   // NNODE
    int* row_ptr  = hist + NNODE;            // NNODE+1
    int* cursor   = row_ptr + NNODE + 1;     // NNODE
    int* col_src  = cursor + NNODE;          // NEDGE
    int* blockSum = col_src + NEDGE;         // NSBLK
    int* blockOff = blockSum + NSBLK;        // NSBLK

    const float* wb1 = w1a + 16 * 64;
    const float* wb2 = w2a + 64 * 64;

    const int NBLK = (NNODE + 255) / 256;
    const int EBLK = (NEDGE + 255) / 256;
    const int N16  = (NNODE * 16 + 255) / 256;

    // CSR build (shared by both layers)
    hipMemsetAsync(hist, 0, (size_t)NNODE * sizeof(int), stream);
    edge_hist<<<EBLK, 256, 0, stream>>>(ei, hist);
    scan_phase_a<<<NSBLK, 256, 0, stream>>>(hist, blockSum);
    scan_phase_b<<<1, 256, 0, stream>>>(blockSum, blockOff);
    scan_phase_c<<<NSBLK, 256, 0, stream>>>(hist, blockOff, row_ptr, cursor);
    edge_fill<<<EBLK, 256, 0, stream>>>(ei, cursor, col_src);

    prep_weights<<<16, 256, 0, stream>>>(w1a, w2a, wt1, wt2);
    node_pre1<<<NBLK, 256, 0, stream>>>(x, wt1, wb1, b1a, pA, pB);

    // Layer 1: CSR aggregation
    csr_aggregate<<<N16, 256, 0, stream>>>(pA, pB, row_ptr, col_src, acc, cnt);

    node_mid<<<NBLK, 256, 0, stream>>>(acc, cnt, w1b, b1b, wt2, wb2, b2a, pA, pB);

    // Layer 2: CSR aggregation
    csr_aggregate<<<N16, 256, 0, stream>>>(pA, pB, row_ptr, col_src, acc, cnt);

    node_final<<<NBLK, 256, 0, stream>>>(acc, cnt, w2b, b2b, wl, bl, out);
}

// Round 13
// 382.309 us; speedup vs baseline: 3.2180x; 1.1148x over previous
//
#include <hip/hip_runtime.h>

#define NEDGE 800000
#define NNODE 50000
#define NSBLK ((NNODE + 255) / 256)   // 196 scan blocks
// dims: IN=16, HID=64, OUT=2

// ---------------------------------------------------------------------------
// wt = W_top - W_bot for both layers' first linear.
// w1a: [32,64] rows 0..15 = xi, 16..31 = (xj-xi).  w2a: [128,64] similarly.
// ---------------------------------------------------------------------------
__global__ void prep_weights(const float* __restrict__ w1a,
                             const float* __restrict__ w2a,
                             float* __restrict__ wt1,
                             float* __restrict__ wt2) {
    int i = blockIdx.x * blockDim.x + threadIdx.x;
    if (i < 16 * 64) wt1[i] = w1a[i] - w1a[16 * 64 + i];
    if (i < 64 * 64) wt2[i] = w2a[i] - w2a[64 * 64 + i];
}

// ---------------------------------------------------------------------------
// CSR build step 1: histogram of dst
// ---------------------------------------------------------------------------
__global__ __launch_bounds__(256) void edge_hist(const int* __restrict__ ei,
                                                 int* __restrict__ hist) {
    int e = blockIdx.x * blockDim.x + threadIdx.x;
    if (e >= NEDGE) return;
    atomicAdd(hist + ei[NEDGE + e], 1);
}

// ---------------------------------------------------------------------------
// CSR build step 2: multi-block exclusive scan (A: reduce, B: scan sums,
// C: local scan + offset, coalesced)
// ---------------------------------------------------------------------------
__global__ __launch_bounds__(256) void scan_phase_a(const int* __restrict__ hist,
                                                    int* __restrict__ blockSums) {
    __shared__ int sh[256];
    int t = threadIdx.x;
    int n = blockIdx.x * 256 + t;
    sh[t] = (n < NNODE) ? hist[n] : 0;
    __syncthreads();
#pragma unroll
    for (int off = 128; off > 0; off >>= 1) {
        if (t < off) sh[t] += sh[t + off];
        __syncthreads();
    }
    if (t == 0) blockSums[blockIdx.x] = sh[0];
}

__global__ __launch_bounds__(256) void scan_phase_b(const int* __restrict__ blockSums,
                                                    int* __restrict__ blockOff) {
    __shared__ int sh[256];
    int t = threadIdx.x;
    int v = (t < NSBLK) ? blockSums[t] : 0;
    sh[t] = v;
    __syncthreads();
#pragma unroll
    for (int off = 1; off < 256; off <<= 1) {
        int u = (t >= off) ? sh[t - off] : 0;
        __syncthreads();
        sh[t] += u;
        __syncthreads();
    }
    if (t < NSBLK) blockOff[t] = sh[t] - v;  // exclusive
}

__global__ __launch_bounds__(256) void scan_phase_c(const int* __restrict__ hist,
                                                    const int* __restrict__ blockOff,
                                                    int* __restrict__ row_ptr,
                                                    int* __restrict__ cursor) {
    __shared__ int sh[256];
    int t = threadIdx.x;
    int n = blockIdx.x * 256 + t;
    int v = (n < NNODE) ? hist[n] : 0;
    sh[t] = v;
    __syncthreads();
#pragma unroll
    for (int off = 1; off < 256; off <<= 1) {
        int u = (t >= off) ? sh[t - off] : 0;
        __syncthreads();
        sh[t] += u;
        __syncthreads();
    }
    int ex = blockOff[blockIdx.x] + sh[t] - v;  // exclusive prefix
    if (n < NNODE) {
        row_ptr[n] = ex;
        cursor[n] = ex;
    }
    if (blockIdx.x == 0 && t == 0) row_ptr[NNODE] = NEDGE;
}

// ---------------------------------------------------------------------------
// CSR build step 3: fill column (src) list
// ---------------------------------------------------------------------------
__global__ __launch_bounds__(256) void edge_fill(const int* __restrict__ ei,
                                                 int* __restrict__ cursor,
                                                 int* __restrict__ col_src) {
    int e = blockIdx.x * blockDim.x + threadIdx.x;
    if (e >= NEDGE) return;
    int s = ei[e];
    int d = ei[NEDGE + e];
    int slot = atomicAdd(cursor + d, 1);
    col_src[slot] = s;
}

// ---------------------------------------------------------------------------
// node_pre1 v2: 16 lanes per node; lane c owns output cols 4c..4c+3.
//   pA[n] = x[n]@wt1 + b1a,  pB[n] = x[n]@wb1
// ---------------------------------------------------------------------------
__global__ __launch_bounds__(256) void node_pre1(
    const float* __restrict__ x, const float* __restrict__ wt1,
    const float* __restrict__ wb1, const float* __restrict__ b1a,
    float* __restrict__ pA, float* __restrict__ pB) {
    int t = blockIdx.x * blockDim.x + threadIdx.x;
    int n = t >> 4;
    int c = t & 15;
    if (n >= NNODE) return;
    const float* xr = x + (size_t)n * 16;
    float4 a = *(const float4*)(b1a + c * 4);
    float4 b = make_float4(0.f, 0.f, 0.f, 0.f);
#pragma unroll
    for (int k = 0; k < 16; ++k) {
        float xk = xr[k];  // uniform within 16-lane group (L1 broadcast)
        float4 wa = *(const float4*)(wt1 + k * 64 + c * 4);
        float4 wb = *(const float4*)(wb1 + k * 64 + c * 4);
        a.x = fmaf(xk, wa.x, a.x); a.y = fmaf(xk, wa.y, a.y);
        a.z = fmaf(xk, wa.z, a.z); a.w = fmaf(xk, wa.w, a.w);
        b.x = fmaf(xk, wb.x, b.x); b.y = fmaf(xk, wb.y, b.y);
        b.z = fmaf(xk, wb.z, b.z); b.w = fmaf(xk, wb.w, b.w);
    }
    *(float4*)(pA + (size_t)n * 64 + c * 4) = a;
    *(float4*)(pB + (size_t)n * 64 + c * 4) = b;
}

// ---------------------------------------------------------------------------
// CSR aggregation, 16 lanes per node (unchanged — proven fast):
//   acc[n] = sum_e relu(pA[n] + pB[col_src[e]]);  cnt[n] = deg(n)
// ---------------------------------------------------------------------------
__global__ __launch_bounds__(256) void csr_aggregate(
    const float* __restrict__ pA, const float* __restrict__ pB,
    const int* __restrict__ row_ptr, const int* __restrict__ col_src,
    float* __restrict__ acc, float* __restrict__ cnt) {
    int t = blockIdx.x * blockDim.x + threadIdx.x;
    int n = t >> 4;
    int c = t & 15;
    if (n >= NNODE) return;
    int beg = row_ptr[n];
    int end = row_ptr[n + 1];
    float4 av = *(const float4*)(pA + (size_t)n * 64 + c * 4);
    float sx = 0.0f, sy = 0.0f, sz = 0.0f, sw = 0.0f;
    for (int e = beg; e < end; ++e) {
        int s = col_src[e];
        float4 bv = *(const float4*)(pB + (size_t)s * 64 + c * 4);
        sx += fmaxf(av.x + bv.x, 0.0f);
        sy += fmaxf(av.y + bv.y, 0.0f);
        sz += fmaxf(av.z + bv.z, 0.0f);
        sw += fmaxf(av.w + bv.w, 0.0f);
    }
    *(float4*)(acc + (size_t)n * 64 + c * 4) = make_float4(sx, sy, sz, sw);
    if (c == 0) cnt[n] = (float)(end - beg);
}

// ---------------------------------------------------------------------------
// node_mid v2: 16 lanes per node, 16 nodes per block. Row data via padded LDS.
//   h1 = (cnt>0) ? relu((acc/cnt)@w1b + b1b) : 0
//   pA = h1@wt2 + b2a,  pB = h1@wb2
// ---------------------------------------------------------------------------
__global__ __launch_bounds__(256) void node_mid(
    const float* __restrict__ acc, const float* __restrict__ cnt,
    const float* __restrict__ w1b, const float* __restrict__ b1b,
    const float* __restrict__ wt2, const float* __restrict__ wb2,
    const float* __restrict__ b2a,
    float* __restrict__ pA, float* __restrict__ pB) {
    __shared__ float mrow[16][68];  // +4 pad: spread banks across node groups
    __shared__ float hrow[16][68];
    int tid = threadIdx.x;
    int ln = tid >> 4;
    int c = tid & 15;
    int n = blockIdx.x * 16 + ln;   // grid is exact: 3125*16 = 50000
    float cv = cnt[n];
    float inv = (cv > 0.0f) ? 1.0f / cv : 0.0f;
    float4 av = *(const float4*)(acc + (size_t)n * 64 + c * 4);
    mrow[ln][c * 4 + 0] = av.x * inv;
    mrow[ln][c * 4 + 1] = av.y * inv;
    mrow[ln][c * 4 + 2] = av.z * inv;
    mrow[ln][c * 4 + 3] = av.w * inv;
    __syncthreads();

    float4 h = *(const float4*)(b1b + c * 4);
#pragma unroll 8
    for (int k = 0; k < 64; ++k) {
        float mk = mrow[ln][k];          // same-addr broadcast in 16-lane group
        float4 w = *(const float4*)(w1b + k * 64 + c * 4);
        h.x = fmaf(mk, w.x, h.x); h.y = fmaf(mk, w.y, h.y);
        h.z = fmaf(mk, w.z, h.z); h.w = fmaf(mk, w.w, h.w);
    }
    bool live = (cv > 0.0f);
    hrow[ln][c * 4 + 0] = live ? fmaxf(h.x, 0.0f) : 0.0f;
    hrow[ln][c * 4 + 1] = live ? fmaxf(h.y, 0.0f) : 0.0f;
    hrow[ln][c * 4 + 2] = live ? fmaxf(h.z, 0.0f) : 0.0f;
    hrow[ln][c * 4 + 3] = live ? fmaxf(h.w, 0.0f) : 0.0f;
    __syncthreads();

    float4 a = *(const float4*)(b2a + c * 4);
    float4 b = make_float4(0.f, 0.f, 0.f, 0.f);
#pragma unroll 8
    for (int k = 0; k < 64; ++k) {
        float hk = hrow[ln][k];
        float4 wa = *(const float4*)(wt2 + k * 64 + c * 4);
        float4 wb = *(const float4*)(wb2 + k * 64 + c * 4);
        a.x = fmaf(hk, wa.x, a.x); a.y = fmaf(hk, wa.y, a.y);
        a.z = fmaf(hk, wa.z, a.z); a.w = fmaf(hk, wa.w, a.w);
        b.x = fmaf(hk, wb.x, b.x); b.y = fmaf(hk, wb.y, b.y);
        b.z = fmaf(hk, wb.z, b.z); b.w = fmaf(hk, wb.w, b.w);
    }
    *(float4*)(pA + (size_t)n * 64 + c * 4) = a;
    *(float4*)(pB + (size_t)n * 64 + c * 4) = b;
}

// ---------------------------------------------------------------------------
// node_final v2: 16 lanes per node; per-lane partial dot with wl, then
// shfl_xor reduce over the 16-lane group.
//   h2 = (cnt>0) ? relu((acc/cnt)@w2b + b2b) : 0;  out = h2@wl + bl
// ---------------------------------------------------------------------------
__global__ __launch_bounds__(256) void node_final(
    const float* __restrict__ acc, const float* __restrict__ cnt,
    const float* __restrict__ w2b, const float* __restrict__ b2b,
    const float* __restrict__ wl, const float* __restrict__ bl,
    float* __restrict__ out) {
    __shared__ float mrow[16][68];
    int tid = threadIdx.x;
    int ln = tid >> 4;
    int c = tid & 15;
    int n = blockIdx.x * 16 + ln;
    float cv = cnt[n];
    float inv = (cv > 0.0f) ? 1.0f / cv : 0.0f;
    float4 av = *(const float4*)(acc + (size_t)n * 64 + c * 4);
    mrow[ln][c * 4 + 0] = av.x * inv;
    mrow[ln][c * 4 + 1] = av.y * inv;
    mrow[ln][c * 4 + 2] = av.z * inv;
    mrow[ln][c * 4 + 3] = av.w * inv;
    __syncthreads();

    float4 h = *(const float4*)(b2b + c * 4);
#pragma unroll 8
    for (int k = 0; k < 64; ++k) {
        float mk = mrow[ln][k];
        float4 w = *(const float4*)(w2b + k * 64 + c * 4);
        h.x = fmaf(mk, w.x, h.x); h.y = fmaf(mk, w.y, h.y);
        h.z = fmaf(mk, w.z, h.z); h.w = fmaf(mk, w.w, h.w);
    }
    bool live = (cv > 0.0f);
    float h0 = live ? fmaxf(h.x, 0.0f) : 0.0f;
    float h1v = live ? fmaxf(h.y, 0.0f) : 0.0f;
    float h2v = live ? fmaxf(h.z, 0.0f) : 0.0f;
    float h3 = live ? fmaxf(h.w, 0.0f) : 0.0f;

    int j = c * 4;
    float o0 = h0 * wl[(j + 0) * 2 + 0] + h1v * wl[(j + 1) * 2 + 0] +
               h2v * wl[(j + 2) * 2 + 0] + h3 * wl[(j + 3) * 2 + 0];
    float o1 = h0 * wl[(j + 0) * 2 + 1] + h1v * wl[(j + 1) * 2 + 1] +
               h2v * wl[(j + 2) * 2 + 1] + h3 * wl[(j + 3) * 2 + 1];
#pragma unroll
    for (int off = 1; off < 16; off <<= 1) {
        o0 += __shfl_xor(o0, off, 16);
        o1 += __shfl_xor(o1, off, 16);
    }
    if (c == 0) {
        out[(size_t)n * 2 + 0] = o0 + bl[0];
        out[(size_t)n * 2 + 1] = o1 + bl[1];
    }
}

// ---------------------------------------------------------------------------
extern "C" void kernel_launch(void* const* d_in, const int* in_sizes, int n_in,
                              void* d_out, int out_size, void* d_ws, size_t ws_size,
                              hipStream_t stream) {
    const float* x   = (const float*)d_in[0];
    const int*   ei  = (const int*)d_in[1];
    const float* w1a = (const float*)d_in[2];
    const float* b1a = (const float*)d_in[3];
    const float* w1b = (const float*)d_in[4];
    const float* b1b = (const float*)d_in[5];
    const float* w2a = (const float*)d_in[6];
    const float* b2a = (const float*)d_in[7];
    const float* w2b = (const float*)d_in[8];
    const float* b2b = (const float*)d_in[9];
    const float* wl  = (const float*)d_in[10];
    const float* bl  = (const float*)d_in[11];
    float* out = (float*)d_out;

    // workspace layout
    float* acc    = (float*)d_ws;            // NNODE*64
    float* cnt    = acc + NNODE * 64;        // NNODE
    float* pA     = cnt + NNODE;             // NNODE*64
    float* pB     = pA + NNODE * 64;         // NNODE*64
    float* wt1    = pB + NNODE * 64;         // 16*64
    float* wt2    = wt1 + 16 * 64;           // 64*64
    int* hist     = (int*)(wt2 + 64 * 64);   // NNODE
    int* row_ptr  = hist + NNODE;            // NNODE+1
    int* cursor   = row_ptr + NNODE + 1;     // NNODE
    int* col_src  = cursor + NNODE;          // NEDGE
    int* blockSum = col_src + NEDGE;         // NSBLK
    int* blockOff = blockSum + NSBLK;        // NSBLK

    const float* wb1 = w1a + 16 * 64;
    const float* wb2 = w2a + 64 * 64;

    const int EBLK = (NEDGE + 255) / 256;
    const int N16  = (NNODE * 16 + 255) / 256;  // 3125 blocks, exact

    // CSR build (shared by both layers)
    hipMemsetAsync(hist, 0, (size_t)NNODE * sizeof(int), stream);
    edge_hist<<<EBLK, 256, 0, stream>>>(ei, hist);
    scan_phase_a<<<NSBLK, 256, 0, stream>>>(hist, blockSum);
    scan_phase_b<<<1, 256, 0, stream>>>(blockSum, blockOff);
    scan_phase_c<<<NSBLK, 256, 0, stream>>>(hist, blockOff, row_ptr, cursor);
    edge_fill<<<EBLK, 256, 0, stream>>>(ei, cursor, col_src);

    prep_weights<<<16, 256, 0, stream>>>(w1a, w2a, wt1, wt2);
    node_pre1<<<N16, 256, 0, stream>>>(x, wt1, wb1, b1a, pA, pB);

    // Layer 1: CSR aggregation
    csr_aggregate<<<N16, 256, 0, stream>>>(pA, pB, row_ptr, col_src, acc, cnt);

    node_mid<<<N16, 256, 0, stream>>>(acc, cnt, w1b, b1b, wt2, wb2, b2a, pA, pB);

    // Layer 2: CSR aggregation
    csr_aggregate<<<N16, 256, 0, stream>>>(pA, pB, row_ptr, col_src, acc, cnt);

    node_final<<<N16, 256, 0, stream>>>(acc, cnt, w2b, b2b, wl, bl, out);
}